// Round 9
// baseline (108.695 us; speedup 1.0000x reference)
//
#include <hip/hip_runtime.h>
#include <math.h>

// Problem constants (fixed by the reference setup_inputs)
#define BB 2
#define VV 3
#define CC 8
#define HH 128
#define WW 160
#define DD 64
constexpr int HW = HH * WW;
constexpr int NPIX = BB * HW;            // 40960
constexpr int PX_PER_BLOCK = 32;         // consecutive pixels per block
constexpr int CHUNKS = 8;                // depth chunks per pixel
constexpr int DPC = DD / CHUNKS;         // 8 depths per thread

typedef _Float16 h8 __attribute__((ext_vector_type(8)));

static __device__ __forceinline__ h8 splat8(float x) {
    const _Float16 v = (_Float16)x;
    h8 r = {v, v, v, v, v, v, v, v};
    return r;
}

// ---------------------------------------------------------------------------
// Prep: transpose+quantize features [V,B,C,H,W] fp32 -> [V,B,H*W] h8 (fp16).
// One bilinear corner = one 16B load.
// ---------------------------------------------------------------------------
__global__ __launch_bounds__(256)
void transpose_feats(const float* __restrict__ feats, h8* __restrict__ ft)
{
    const int t = blockIdx.x * blockDim.x + threadIdx.x;
    if (t >= VV * BB * HW) return;
    const int vb = t / HW;
    const int hw = t - vb * HW;
    const float* src = feats + (size_t)vb * CC * HW + hw;
    h8 v;
#pragma unroll
    for (int c = 0; c < CC; ++c) v[c] = (_Float16)src[(size_t)c * HW];
    ft[(size_t)vb * HW + hw] = v;
}

// ---------------------------------------------------------------------------
// Fully fused: block = 32 consecutive pixels x 8 depth chunks (4 waves),
// 8 depths serial per thread. Corner registers persist across the unrolled
// depth loop and are reloaded ONLY when the integer corner indices change
// (~6%/step): ~2.4x fewer gather bytes than the depth-pair version.
// Geometry in d-form (Rp*d+T)/(Rp2*d+T2): no per-depth rcp(dv).
// Softmax over D=64: thread-local over 8 regs + xor32 shuffle + 4-wave LDS.
// NO launch_bounds cap (round-3 spill lesson) - watch WRITE_SIZE.
// ---------------------------------------------------------------------------
__global__ __launch_bounds__(256)
void depthnet_fused(const h8* __restrict__ ft,         // [V,B,H*W] fp16x8
                    const float* __restrict__ proj,    // [B,V,3,4]
                    const float* __restrict__ depthv,  // [B,D,H,W]
                    const float* __restrict__ regw,    // [C]
                    float* __restrict__ out)           // [B,H,W]
{
    __shared__ float sm_m[4 * PX_PER_BLOCK];
    __shared__ float sm_l[4 * PX_PER_BLOCK];
    __shared__ float sm_s[4 * PX_PER_BLOCK];

    const int tid   = threadIdx.x;
    const int lane  = tid & 63;
    const int wave  = tid >> 6;              // 0..3
    const int px    = lane & 31;             // pixel within block
    const int sub   = lane >> 5;             // 0/1
    const int chunk = wave * 2 + sub;        // 0..7
    const int pixel = blockIdx.x * PX_PER_BLOCK + px;

    const int b  = (pixel >= HW) ? 1 : 0;
    const int hw = pixel - b * HW;
    const int h  = hw / WW;
    const int w  = hw - h * WW;

    // reference-view features (one 16B fp16 load)
    float rf[CC], rf2[CC];
    {
        h8 rv = ft[(size_t)b * HW + hw];
#pragma unroll
        for (int c = 0; c < CC; ++c) { rf[c] = (float)rv[c]; rf2[c] = rf[c] * rf[c]; }
    }

    // per-view projection rows applied to (x, y, 1); T columns
    float Rp[2][3], Tv[2][3];
    const float xf = (float)w, yf = (float)h;
#pragma unroll
    for (int v = 0; v < 2; ++v) {
        const float* M = proj + ((size_t)b * VV + (v + 1)) * 12;
#pragma unroll
        for (int j = 0; j < 3; ++j) {
            Rp[v][j] = M[j * 4 + 0] * xf + M[j * 4 + 1] * yf + M[j * 4 + 2];
            Tv[v][j] = M[j * 4 + 3];
        }
    }

    const h8* fsrc0 = ft + (size_t)(1 * BB + b) * HW;
    const h8* fsrc1 = ft + (size_t)(2 * BB + b) * HW;

    // preload this chunk's 8 depth values (coalesced, issued together)
    const float* dvp = depthv + (size_t)b * DD * HW + hw;
    float dvv[DPC];
#pragma unroll
    for (int k = 0; k < DPC; ++k) dvv[k] = dvp[(size_t)(chunk * DPC + k) * HW];

    float cost[DPC];
    h8 A0, A1, A2, A3, B0, B1, B2, B3;      // persistent corner registers
    int pa0 = 0, pa3 = 0, pb0 = 0, pb3 = 0; // previous corner indices

#pragma unroll
    for (int k = 0; k < DPC; ++k) {
        const float d = dvv[k];

        // ---- geometry (d-form, no rcp(dv)) ----
        float wt[2][4];
        int   ib[2][4];
        float nmask = 1.0f;
#pragma unroll
        for (int v = 0; v < 2; ++v) {
            const float sx = Rp[v][0] * d + Tv[v][0];
            const float sy = Rp[v][1] * d + Tv[v][1];
            const float sz = Rp[v][2] * d + Tv[v][2];
            const float rsz = __builtin_amdgcn_rcpf(sz);
            const float ix = sx * rsz;       // == (gx+1)*0.5*(W-1)
            const float iy = sy * rsz;
            nmask += ((ix > 0.f) && (ix < (float)(WW - 1)) &&
                      (iy > 0.f) && (iy < (float)(HH - 1))) ? 1.0f : 0.0f;
            const float x0f = floorf(ix), y0f = floorf(iy);
            const float wx1 = ix - x0f, wy1 = iy - y0f;
            const float wx0 = 1.f - wx1, wy0 = 1.f - wy1;
            const float x1f = x0f + 1.f, y1f = y0f + 1.f;
            const bool vx0 = (x0f >= 0.f) && (x0f <= (float)(WW - 1));
            const bool vx1 = (x1f >= 0.f) && (x1f <= (float)(WW - 1));
            const bool vy0 = (y0f >= 0.f) && (y0f <= (float)(HH - 1));
            const bool vy1 = (y1f >= 0.f) && (y1f <= (float)(HH - 1));
            wt[v][0] = wx0 * wy0 * ((vx0 && vy0) ? 1.f : 0.f);
            wt[v][1] = wx1 * wy0 * ((vx1 && vy0) ? 1.f : 0.f);
            wt[v][2] = wx0 * wy1 * ((vx0 && vy1) ? 1.f : 0.f);
            wt[v][3] = wx1 * wy1 * ((vx1 && vy1) ? 1.f : 0.f);
            const int x0c = (int)fminf(fmaxf(x0f, 0.f), (float)(WW - 1));
            const int x1c = (int)fminf(fmaxf(x1f, 0.f), (float)(WW - 1));
            const int y0c = (int)fminf(fmaxf(y0f, 0.f), (float)(HH - 1));
            const int y1c = (int)fminf(fmaxf(y1f, 0.f), (float)(HH - 1));
            ib[v][0] = y0c * WW + x0c;
            ib[v][1] = y0c * WW + x1c;
            ib[v][2] = y1c * WW + x0c;
            ib[v][3] = y1c * WW + x1c;
        }

        // ---- conditional corner (re)load: i00 & i11 match => all 4 match ----
        if (k == 0) {
            A0 = fsrc0[ib[0][0]]; A1 = fsrc0[ib[0][1]];
            A2 = fsrc0[ib[0][2]]; A3 = fsrc0[ib[0][3]];
            B0 = fsrc1[ib[1][0]]; B1 = fsrc1[ib[1][1]];
            B2 = fsrc1[ib[1][2]]; B3 = fsrc1[ib[1][3]];
        } else {
            if (ib[0][0] != pa0 || ib[0][3] != pa3) {
                A0 = fsrc0[ib[0][0]]; A1 = fsrc0[ib[0][1]];
                A2 = fsrc0[ib[0][2]]; A3 = fsrc0[ib[0][3]];
            }
            if (ib[1][0] != pb0 || ib[1][3] != pb3) {
                B0 = fsrc1[ib[1][0]]; B1 = fsrc1[ib[1][1]];
                B2 = fsrc1[ib[1][2]]; B3 = fsrc1[ib[1][3]];
            }
        }
        pa0 = ib[0][0]; pa3 = ib[0][3];
        pb0 = ib[1][0]; pb3 = ib[1][3];

        // ---- packed-f16 interp, fp32 cost ----
        h8 vah = A0 * splat8(wt[0][0]) + A1 * splat8(wt[0][1])
               + A2 * splat8(wt[0][2]) + A3 * splat8(wt[0][3]);
        h8 vbh = B0 * splat8(wt[1][0]) + B1 * splat8(wt[1][1])
               + B2 * splat8(wt[1][2]) + B3 * splat8(wt[1][3]);

        const float cnt = __builtin_amdgcn_rcpf(nmask);
        float t1 = 0.f, t2 = 0.f;
#pragma unroll
        for (int c = 0; c < CC; ++c) {
            const float av = (float)vah[c];
            const float bv = (float)vbh[c];
            const float sum = rf[c] + av + bv;
            const float sq  = rf2[c] + av * av + bv * bv;
            t1 += regw[c] * sq;                    // regw wave-uniform -> scalar
            t2 += (regw[c] * sum) * sum;
        }
        cost[k] = cnt * t1 - (cnt * cnt) * t2;
    }

    // ---- thread-local softmax over the 8 depths (one max, 8 exp) ----
    float m = cost[0];
#pragma unroll
    for (int k = 1; k < DPC; ++k) m = fmaxf(m, cost[k]);
    float l = 0.f, s = 0.f;
#pragma unroll
    for (int k = 0; k < DPC; ++k) {
        const float e = __expf(cost[k] - m);
        l += e;
        s += e * dvv[k];
    }

    // merge the two chunks within the wave (lanes xor 32)
    {
        const float m2 = __shfl_xor(m, 32, 64);
        const float l2 = __shfl_xor(l, 32, 64);
        const float s2 = __shfl_xor(s, 32, 64);
        const float M  = fmaxf(m, m2);
        const float e1 = __expf(m - M);
        const float e2 = __expf(m2 - M);
        l = l * e1 + l2 * e2;
        s = s * e1 + s2 * e2;
        m = M;
    }

    if (lane < PX_PER_BLOCK) {
        sm_m[wave * PX_PER_BLOCK + px] = m;
        sm_l[wave * PX_PER_BLOCK + px] = l;
        sm_s[wave * PX_PER_BLOCK + px] = s;
    }
    __syncthreads();

    if (tid < PX_PER_BLOCK) {
        float M = sm_m[tid], L = sm_l[tid], S = sm_s[tid];
#pragma unroll
        for (int wv = 1; wv < 4; ++wv) {
            const float m2 = sm_m[wv * PX_PER_BLOCK + tid];
            const float l2 = sm_l[wv * PX_PER_BLOCK + tid];
            const float s2 = sm_s[wv * PX_PER_BLOCK + tid];
            const float Mn = fmaxf(M, m2);
            const float e1 = __expf(M - Mn);
            const float e2 = __expf(m2 - Mn);
            L = L * e1 + l2 * e2;
            S = S * e1 + s2 * e2;
            M = Mn;
        }
        out[blockIdx.x * PX_PER_BLOCK + tid] = S / L;
    }
}

extern "C" void kernel_launch(void* const* d_in, const int* in_sizes, int n_in,
                              void* d_out, int out_size, void* d_ws, size_t ws_size,
                              hipStream_t stream) {
    const float* feats  = (const float*)d_in[0];
    const float* proj   = (const float*)d_in[1];
    const float* depthv = (const float*)d_in[2];
    const float* regw   = (const float*)d_in[3];
    float* out = (float*)d_out;
    h8* ft = (h8*)d_ws;                            // [V,B,HW] fp16x8 = 1.97 MB

    {
        const int n = VV * BB * HW;                // 122880
        hipLaunchKernelGGL(transpose_feats, dim3((n + 255) / 256), dim3(256), 0, stream,
                           feats, ft);
    }
    {
        const int grid = NPIX / PX_PER_BLOCK;      // 1280 blocks
        hipLaunchKernelGGL(depthnet_fused, dim3(grid), dim3(256), 0, stream,
                           ft, proj, depthv, regw, out);
    }
}

// Round 10
// 96.419 us; speedup vs baseline: 1.1273x; 1.1273x over previous
//
#include <hip/hip_runtime.h>
#include <math.h>

// Problem constants (fixed by the reference setup_inputs)
#define BB 2
#define VV 3
#define CC 8
#define HH 128
#define WW 160
#define DD 64
constexpr int HW = HH * WW;
constexpr int NPIX = BB * HW;             // 40960
constexpr int PIXBANDS = NPIX / 256;      // 160 bands of 256 px
constexpr int BANDS_PER_XCD = PIXBANDS / 8;  // 20
constexpr int DPT = 4;                    // depths per thread (quad)

typedef _Float16 h8 __attribute__((ext_vector_type(8)));
typedef _Float16 h2 __attribute__((ext_vector_type(2)));

static __device__ __forceinline__ h8 splat8(float x) {
    const _Float16 v = (_Float16)x;
    h8 r = {v, v, v, v, v, v, v, v};
    return r;
}

// ---------------------------------------------------------------------------
// Prep: transpose+quantize features [V,B,C,H,W] fp32 -> [V,B,H*W] h8 (fp16).
// ---------------------------------------------------------------------------
__global__ __launch_bounds__(256)
void transpose_feats(const float* __restrict__ feats, h8* __restrict__ ft)
{
    const int t = blockIdx.x * blockDim.x + threadIdx.x;
    if (t >= VV * BB * HW) return;
    const int vb = t / HW;
    const int hw = t - vb * HW;
    const float* src = feats + (size_t)vb * CC * HW + hw;
    h8 v;
#pragma unroll
    for (int c = 0; c < CC; ++c) v[c] = (_Float16)src[(size_t)c * HW];
    ft[(size_t)vb * HW + hw] = v;
}

// ---------------------------------------------------------------------------
// Cost kernel, DEPTH-QUAD version: one thread per (pixel, 4 consecutive
// depths). Persistent corner registers, conditionally reloaded only when the
// integer corner indices move (~6%/step) -> ~2 gathers/depth vs 8 naive.
// Quad (not octet, R9 lesson): keeps VGPR ~110 -> 4 waves/SIMD, and grid
// stays 2560 blocks = 40 waves/CU of work.
// Emits packed fp16x2 (cost, dv) for the cheap softmax pass.
// ---------------------------------------------------------------------------
__global__ __launch_bounds__(256)
void cost_kernel(const h8* __restrict__ ft,         // [V,B,H*W] fp16x8
                 const float* __restrict__ proj,    // [B,V,3,4]
                 const float* __restrict__ depthv,  // [B,D,H,W]
                 const float* __restrict__ regw,    // [C]
                 h2* __restrict__ pc)               // [B,D,H*W] packed (cost,dv)
{
    // swizzle: xcd = blockIdx & 7 owns a contiguous 20-band pixel group and
    // iterates all depth-quads over it (feature reuse in its L2).
    const int i    = blockIdx.x;
    const int xcd  = i & 7;
    const int idx  = i >> 3;                        // 0..319
    const int band = xcd * BANDS_PER_XCD + (idx % BANDS_PER_XCD);
    const int dq   = idx / BANDS_PER_XCD;           // 0..15
    const int d0   = dq * DPT;
    const int pixel = band * 256 + threadIdx.x;

    const int b  = (pixel >= HW) ? 1 : 0;           // uniform per block
    const int hw = pixel - b * HW;
    const int h  = hw / WW;
    const int w  = hw - h * WW;

    // reference-view features (one 16B fp16 load)
    float rf[CC], rf2[CC];
    {
        h8 rv = ft[(size_t)b * HW + hw];
#pragma unroll
        for (int c = 0; c < CC; ++c) { rf[c] = (float)rv[c]; rf2[c] = rf[c] * rf[c]; }
    }

    // per-view projection rows applied to (x, y, 1); T columns
    float Rp[2][3], Tvv[2][3];
    const float xf = (float)w, yf = (float)h;
#pragma unroll
    for (int v = 0; v < 2; ++v) {
        const float* M = proj + ((size_t)b * VV + (v + 1)) * 12;
#pragma unroll
        for (int j = 0; j < 3; ++j) {
            Rp[v][j]  = M[j * 4 + 0] * xf + M[j * 4 + 1] * yf + M[j * 4 + 2];
            Tvv[v][j] = M[j * 4 + 3];
        }
    }

    const h8* fsrc0 = ft + (size_t)(1 * BB + b) * HW;
    const h8* fsrc1 = ft + (size_t)(2 * BB + b) * HW;

    // this quad's 4 depth values (coalesced, issued together)
    const float* dvp = depthv + (size_t)b * DD * HW + hw;
    float dvv[DPT];
#pragma unroll
    for (int k = 0; k < DPT; ++k) dvv[k] = dvp[(size_t)(d0 + k) * HW];

    const size_t obase = (size_t)b * DD * HW + hw;

    h8 A0, A1, A2, A3, B0, B1, B2, B3;      // persistent corner registers
    int pa0 = -1, pa3 = -1, pb0 = -1, pb3 = -1;

#pragma unroll
    for (int k = 0; k < DPT; ++k) {
        const float d = dvv[k];

        // ---- geometry (d-form: (Rp*d+T)/(Rp2*d+T2), no rcp(dv)) ----
        float wt[2][4];
        int   ib[2][4];
        float nmask = 1.0f;
#pragma unroll
        for (int v = 0; v < 2; ++v) {
            const float sx = Rp[v][0] * d + Tvv[v][0];
            const float sy = Rp[v][1] * d + Tvv[v][1];
            const float sz = Rp[v][2] * d + Tvv[v][2];
            const float rsz = __builtin_amdgcn_rcpf(sz);
            const float ix = sx * rsz;       // == (gx+1)*0.5*(W-1)
            const float iy = sy * rsz;
            nmask += ((ix > 0.f) && (ix < (float)(WW - 1)) &&
                      (iy > 0.f) && (iy < (float)(HH - 1))) ? 1.0f : 0.0f;
            const float x0f = floorf(ix), y0f = floorf(iy);
            const float wx1 = ix - x0f, wy1 = iy - y0f;
            const float wx0 = 1.f - wx1, wy0 = 1.f - wy1;
            const float x1f = x0f + 1.f, y1f = y0f + 1.f;
            const bool vx0 = (x0f >= 0.f) && (x0f <= (float)(WW - 1));
            const bool vx1 = (x1f >= 0.f) && (x1f <= (float)(WW - 1));
            const bool vy0 = (y0f >= 0.f) && (y0f <= (float)(HH - 1));
            const bool vy1 = (y1f >= 0.f) && (y1f <= (float)(HH - 1));
            wt[v][0] = wx0 * wy0 * ((vx0 && vy0) ? 1.f : 0.f);
            wt[v][1] = wx1 * wy0 * ((vx1 && vy0) ? 1.f : 0.f);
            wt[v][2] = wx0 * wy1 * ((vx0 && vy1) ? 1.f : 0.f);
            wt[v][3] = wx1 * wy1 * ((vx1 && vy1) ? 1.f : 0.f);
            const int x0c = (int)fminf(fmaxf(x0f, 0.f), (float)(WW - 1));
            const int x1c = (int)fminf(fmaxf(x1f, 0.f), (float)(WW - 1));
            const int y0c = (int)fminf(fmaxf(y0f, 0.f), (float)(HH - 1));
            const int y1c = (int)fminf(fmaxf(y1f, 0.f), (float)(HH - 1));
            ib[v][0] = y0c * WW + x0c;
            ib[v][1] = y0c * WW + x1c;
            ib[v][2] = y1c * WW + x0c;
            ib[v][3] = y1c * WW + x1c;
        }

        // ---- conditional corner (re)load: i00 & i11 match => all 4 match ----
        if (ib[0][0] != pa0 || ib[0][3] != pa3) {
            A0 = fsrc0[ib[0][0]]; A1 = fsrc0[ib[0][1]];
            A2 = fsrc0[ib[0][2]]; A3 = fsrc0[ib[0][3]];
            pa0 = ib[0][0]; pa3 = ib[0][3];
        }
        if (ib[1][0] != pb0 || ib[1][3] != pb3) {
            B0 = fsrc1[ib[1][0]]; B1 = fsrc1[ib[1][1]];
            B2 = fsrc1[ib[1][2]]; B3 = fsrc1[ib[1][3]];
            pb0 = ib[1][0]; pb3 = ib[1][3];
        }

        // ---- packed-f16 interp, fp32 cost ----
        h8 vah = A0 * splat8(wt[0][0]) + A1 * splat8(wt[0][1])
               + A2 * splat8(wt[0][2]) + A3 * splat8(wt[0][3]);
        h8 vbh = B0 * splat8(wt[1][0]) + B1 * splat8(wt[1][1])
               + B2 * splat8(wt[1][2]) + B3 * splat8(wt[1][3]);

        const float cnt = __builtin_amdgcn_rcpf(nmask);
        float t1 = 0.f, t2 = 0.f;
#pragma unroll
        for (int c = 0; c < CC; ++c) {
            const float av = (float)vah[c];
            const float bv = (float)vbh[c];
            const float sum = rf[c] + av + bv;
            const float sq  = rf2[c] + av * av + bv * bv;
            t1 += regw[c] * sq;                    // regw wave-uniform -> scalar
            t2 += (regw[c] * sum) * sum;
        }
        const float cost = cnt * t1 - (cnt * cnt) * t2;

        h2 pck; pck[0] = (_Float16)cost; pck[1] = (_Float16)d;
        pc[obase + (size_t)(d0 + k) * HW] = pck;   // coalesced 4B store
    }
}

// ---------------------------------------------------------------------------
// Softmax-over-depth: 4 lanes/pixel x 16 depths each, packed (cost,dv) reads
// (one 4B load per depth), online softmax, shuffle merge (xor 16, 32).
// ---------------------------------------------------------------------------
__global__ __launch_bounds__(256)
void softmax_depth(const h2* __restrict__ pc,        // [B,D,H*W] packed
                   float* __restrict__ out)          // [B,H,W]
{
    const int t     = blockIdx.x * blockDim.x + threadIdx.x;
    const int lane  = t & 63;
    const int waveg = t >> 6;
    const int px    = lane & 15;
    const int chunk = lane >> 4;               // 0..3
    const int pixel = waveg * 16 + px;

    const int b  = (pixel >= HW) ? 1 : 0;
    const int hw = pixel - b * HW;

    const h2* cp = pc + (size_t)b * DD * HW + hw;

    float m = -INFINITY, l = 0.f, s = 0.f;
#pragma unroll 4
    for (int j = 0; j < 16; ++j) {
        const int d = chunk * 16 + j;
        const h2 v = cp[(size_t)d * HW];
        const float c  = (float)v[0];
        const float dv = (float)v[1];
        const float M = fmaxf(m, c);
        const float e_old = __expf(m - M);     // exp(-inf)=0 on first iter
        const float e_new = __expf(c - M);
        l = l * e_old + e_new;
        s = s * e_old + e_new * dv;
        m = M;
    }

#pragma unroll
    for (int off = 16; off < 64; off <<= 1) {
        const float m2 = __shfl_xor(m, off, 64);
        const float l2 = __shfl_xor(l, off, 64);
        const float s2 = __shfl_xor(s, off, 64);
        const float M  = fmaxf(m, m2);
        const float e1 = __expf(m - M);
        const float e2 = __expf(m2 - M);
        l = l * e1 + l2 * e2;
        s = s * e1 + s2 * e2;
        m = M;
    }

    if (chunk == 0) out[pixel] = s / l;
}

extern "C" void kernel_launch(void* const* d_in, const int* in_sizes, int n_in,
                              void* d_out, int out_size, void* d_ws, size_t ws_size,
                              hipStream_t stream) {
    const float* feats  = (const float*)d_in[0];
    const float* proj   = (const float*)d_in[1];
    const float* depthv = (const float*)d_in[2];
    const float* regw   = (const float*)d_in[3];
    float* out = (float*)d_out;
    h8* ft = (h8*)d_ws;                                       // 1.97 MB
    h2* pc = (h2*)((char*)d_ws + (size_t)VV * BB * HW * sizeof(h8));  // 10.5 MB

    {
        const int n = VV * BB * HW;                    // 122880
        hipLaunchKernelGGL(transpose_feats, dim3((n + 255) / 256), dim3(256), 0, stream,
                           feats, ft);
    }
    {
        const int grid = (DD / DPT) * PIXBANDS;        // 2560 blocks
        hipLaunchKernelGGL(cost_kernel, dim3(grid), dim3(256), 0, stream,
                           ft, proj, depthv, regw, pc);
    }
    {
        const int total = NPIX * 4;                    // 4 lanes per pixel
        hipLaunchKernelGGL(softmax_depth, dim3(total / 256), dim3(256), 0, stream,
                           pc, out);
    }
}

// Round 11
// 95.353 us; speedup vs baseline: 1.1399x; 1.0112x over previous
//
#include <hip/hip_runtime.h>
#include <math.h>

// Problem constants (fixed by the reference setup_inputs)
#define BB 2
#define VV 3
#define CC 8
#define HH 128
#define WW 160
#define DD 64
constexpr int HW = HH * WW;
constexpr int NPIX = BB * HW;            // 40960
constexpr int PX_PER_BLOCK = 16;         // consecutive pixels per block
constexpr int DPT = 4;                   // depths per thread
constexpr int GRID_FUSED = NPIX / PX_PER_BLOCK;  // 2560
constexpr int XCD_STRIDE = GRID_FUSED / 8;       // 320

typedef _Float16 h8 __attribute__((ext_vector_type(8)));

static __device__ __forceinline__ h8 splat8(float x) {
    const _Float16 v = (_Float16)x;
    h8 r = {v, v, v, v, v, v, v, v};
    return r;
}

// ---------------------------------------------------------------------------
// Prep: transpose+quantize features [V,B,C,H,W] fp32 -> [V,B,H*W] h8 (fp16).
// One bilinear corner = one 16B load.
// ---------------------------------------------------------------------------
__global__ __launch_bounds__(256)
void transpose_feats(const float* __restrict__ feats, h8* __restrict__ ft)
{
    const int t = blockIdx.x * blockDim.x + threadIdx.x;
    if (t >= VV * BB * HW) return;
    const int vb = t / HW;
    const int hw = t - vb * HW;
    const float* src = feats + (size_t)vb * CC * HW + hw;
    h8 v;
#pragma unroll
    for (int c = 0; c < CC; ++c) v[c] = (_Float16)src[(size_t)c * HW];
    ft[(size_t)vb * HW + hw] = v;
}

// ---------------------------------------------------------------------------
// Fully fused cost+softmax: block = 16 consecutive px x 16 depth chunks
// (4 waves), 4 depths serial per thread. R10's persistent-corner conditional
// reload (~2 gathers/depth) + R4's merge tree; no cost-volume round-trip,
// no third kernel. DPT=4 (not 8): R9's 8-deep version hit 192 VGPR ->
// 9% occupancy. Thread-local softmax over 4 register costs.
// NO launch_bounds cap; WRITE_SIZE is the spill canary (expect ~160 KB).
// ---------------------------------------------------------------------------
__global__ __launch_bounds__(256)
void depthnet_fused(const h8* __restrict__ ft,         // [V,B,H*W] fp16x8
                    const float* __restrict__ proj,    // [B,V,3,4]
                    const float* __restrict__ depthv,  // [B,D,H,W]
                    const float* __restrict__ regw,    // [C]
                    float* __restrict__ out)           // [B,H,W]
{
    __shared__ float sm_m[4 * PX_PER_BLOCK];
    __shared__ float sm_l[4 * PX_PER_BLOCK];
    __shared__ float sm_s[4 * PX_PER_BLOCK];

    const int tid   = threadIdx.x;
    const int lane  = tid & 63;
    const int wave  = tid >> 6;              // 0..3
    const int px    = lane & 15;             // pixel within block
    const int sub   = lane >> 4;             // 0..3
    const int chunk = wave * 4 + sub;        // 0..15
    const int d0    = chunk * DPT;
    // XCD swizzle: contiguous pixel band per XCD for L2 locality
    const int bswz  = (blockIdx.x & 7) * XCD_STRIDE + (blockIdx.x >> 3);
    const int pixel = bswz * PX_PER_BLOCK + px;

    const int b  = (pixel >= HW) ? 1 : 0;
    const int hw = pixel - b * HW;
    const int h  = hw / WW;
    const int w  = hw - h * WW;

    // reference-view features (one 16B fp16 load)
    float rf[CC], rf2[CC];
    {
        h8 rv = ft[(size_t)b * HW + hw];
#pragma unroll
        for (int c = 0; c < CC; ++c) { rf[c] = (float)rv[c]; rf2[c] = rf[c] * rf[c]; }
    }

    // per-view projection rows applied to (x, y, 1); T columns
    float Rp[2][3], Tv[2][3];
    const float xf = (float)w, yf = (float)h;
#pragma unroll
    for (int v = 0; v < 2; ++v) {
        const float* M = proj + ((size_t)b * VV + (v + 1)) * 12;
#pragma unroll
        for (int j = 0; j < 3; ++j) {
            Rp[v][j] = M[j * 4 + 0] * xf + M[j * 4 + 1] * yf + M[j * 4 + 2];
            Tv[v][j] = M[j * 4 + 3];
        }
    }

    const h8* fsrc0 = ft + (size_t)(1 * BB + b) * HW;
    const h8* fsrc1 = ft + (size_t)(2 * BB + b) * HW;

    // this chunk's 4 depth values (coalesced, issued together)
    const float* dvp = depthv + (size_t)b * DD * HW + hw;
    float dvv[DPT];
#pragma unroll
    for (int k = 0; k < DPT; ++k) dvv[k] = dvp[(size_t)(d0 + k) * HW];

    float cost[DPT];
    h8 A0, A1, A2, A3, B0, B1, B2, B3;      // persistent corner registers
    int pa0 = -1, pa3 = -1, pb0 = -1, pb3 = -1;

#pragma unroll
    for (int k = 0; k < DPT; ++k) {
        const float d = dvv[k];

        // ---- geometry (d-form: (Rp*d+T)/(Rp2*d+T2), no rcp(dv)) ----
        float wt[2][4];
        int   ib[2][4];
        float nmask = 1.0f;
#pragma unroll
        for (int v = 0; v < 2; ++v) {
            const float sx = Rp[v][0] * d + Tv[v][0];
            const float sy = Rp[v][1] * d + Tv[v][1];
            const float sz = Rp[v][2] * d + Tv[v][2];
            const float rsz = __builtin_amdgcn_rcpf(sz);
            const float ix = sx * rsz;       // == (gx+1)*0.5*(W-1)
            const float iy = sy * rsz;
            nmask += ((ix > 0.f) && (ix < (float)(WW - 1)) &&
                      (iy > 0.f) && (iy < (float)(HH - 1))) ? 1.0f : 0.0f;
            const float x0f = floorf(ix), y0f = floorf(iy);
            const float wx1 = ix - x0f, wy1 = iy - y0f;
            const float wx0 = 1.f - wx1, wy0 = 1.f - wy1;
            const float x1f = x0f + 1.f, y1f = y0f + 1.f;
            const bool vx0 = (x0f >= 0.f) && (x0f <= (float)(WW - 1));
            const bool vx1 = (x1f >= 0.f) && (x1f <= (float)(WW - 1));
            const bool vy0 = (y0f >= 0.f) && (y0f <= (float)(HH - 1));
            const bool vy1 = (y1f >= 0.f) && (y1f <= (float)(HH - 1));
            wt[v][0] = wx0 * wy0 * ((vx0 && vy0) ? 1.f : 0.f);
            wt[v][1] = wx1 * wy0 * ((vx1 && vy0) ? 1.f : 0.f);
            wt[v][2] = wx0 * wy1 * ((vx0 && vy1) ? 1.f : 0.f);
            wt[v][3] = wx1 * wy1 * ((vx1 && vy1) ? 1.f : 0.f);
            const int x0c = (int)fminf(fmaxf(x0f, 0.f), (float)(WW - 1));
            const int x1c = (int)fminf(fmaxf(x1f, 0.f), (float)(WW - 1));
            const int y0c = (int)fminf(fmaxf(y0f, 0.f), (float)(HH - 1));
            const int y1c = (int)fminf(fmaxf(y1f, 0.f), (float)(HH - 1));
            ib[v][0] = y0c * WW + x0c;
            ib[v][1] = y0c * WW + x1c;
            ib[v][2] = y1c * WW + x0c;
            ib[v][3] = y1c * WW + x1c;
        }

        // ---- conditional corner (re)load: i00 & i11 match => all 4 match ----
        if (ib[0][0] != pa0 || ib[0][3] != pa3) {
            A0 = fsrc0[ib[0][0]]; A1 = fsrc0[ib[0][1]];
            A2 = fsrc0[ib[0][2]]; A3 = fsrc0[ib[0][3]];
            pa0 = ib[0][0]; pa3 = ib[0][3];
        }
        if (ib[1][0] != pb0 || ib[1][3] != pb3) {
            B0 = fsrc1[ib[1][0]]; B1 = fsrc1[ib[1][1]];
            B2 = fsrc1[ib[1][2]]; B3 = fsrc1[ib[1][3]];
            pb0 = ib[1][0]; pb3 = ib[1][3];
        }

        // ---- packed-f16 interp, fp32 cost ----
        h8 vah = A0 * splat8(wt[0][0]) + A1 * splat8(wt[0][1])
               + A2 * splat8(wt[0][2]) + A3 * splat8(wt[0][3]);
        h8 vbh = B0 * splat8(wt[1][0]) + B1 * splat8(wt[1][1])
               + B2 * splat8(wt[1][2]) + B3 * splat8(wt[1][3]);

        const float cnt = __builtin_amdgcn_rcpf(nmask);
        float t1 = 0.f, t2 = 0.f;
#pragma unroll
        for (int c = 0; c < CC; ++c) {
            const float av = (float)vah[c];
            const float bv = (float)vbh[c];
            const float sum = rf[c] + av + bv;
            const float sq  = rf2[c] + av * av + bv * bv;
            t1 += regw[c] * sq;                    // regw wave-uniform -> scalar
            t2 += (regw[c] * sum) * sum;
        }
        cost[k] = cnt * t1 - (cnt * cnt) * t2;
    }

    // ---- thread-local softmax over the 4 depths (one max, 4 exp) ----
    float m = fmaxf(fmaxf(cost[0], cost[1]), fmaxf(cost[2], cost[3]));
    float l = 0.f, s = 0.f;
#pragma unroll
    for (int k = 0; k < DPT; ++k) {
        const float e = __expf(cost[k] - m);
        l += e;
        s += e * dvv[k];
    }

    // merge the 4 chunks within the wave (lanes xor 16, 32)
#pragma unroll
    for (int off = 16; off < 64; off <<= 1) {
        const float m2 = __shfl_xor(m, off, 64);
        const float l2 = __shfl_xor(l, off, 64);
        const float s2 = __shfl_xor(s, off, 64);
        const float M  = fmaxf(m, m2);
        const float e1 = __expf(m - M);
        const float e2 = __expf(m2 - M);
        l = l * e1 + l2 * e2;
        s = s * e1 + s2 * e2;
        m = M;
    }

    if (lane < PX_PER_BLOCK) {
        sm_m[wave * PX_PER_BLOCK + px] = m;
        sm_l[wave * PX_PER_BLOCK + px] = l;
        sm_s[wave * PX_PER_BLOCK + px] = s;
    }
    __syncthreads();

    if (tid < PX_PER_BLOCK) {
        float M = sm_m[tid], L = sm_l[tid], S = sm_s[tid];
#pragma unroll
        for (int wv = 1; wv < 4; ++wv) {
            const float m2 = sm_m[wv * PX_PER_BLOCK + tid];
            const float l2 = sm_l[wv * PX_PER_BLOCK + tid];
            const float s2 = sm_s[wv * PX_PER_BLOCK + tid];
            const float Mn = fmaxf(M, m2);
            const float e1 = __expf(M - Mn);
            const float e2 = __expf(m2 - Mn);
            L = L * e1 + l2 * e2;
            S = S * e1 + s2 * e2;
            M = Mn;
        }
        out[bswz * PX_PER_BLOCK + tid] = S / L;
    }
}

extern "C" void kernel_launch(void* const* d_in, const int* in_sizes, int n_in,
                              void* d_out, int out_size, void* d_ws, size_t ws_size,
                              hipStream_t stream) {
    const float* feats  = (const float*)d_in[0];
    const float* proj   = (const float*)d_in[1];
    const float* depthv = (const float*)d_in[2];
    const float* regw   = (const float*)d_in[3];
    float* out = (float*)d_out;
    h8* ft = (h8*)d_ws;                            // [V,B,HW] fp16x8 = 1.97 MB

    {
        const int n = VV * BB * HW;                // 122880
        hipLaunchKernelGGL(transpose_feats, dim3((n + 255) / 256), dim3(256), 0, stream,
                           feats, ft);
    }
    {
        hipLaunchKernelGGL(depthnet_fused, dim3(GRID_FUSED), dim3(256), 0, stream,
                           ft, proj, depthv, regw, out);
    }
}